// Round 6
// baseline (352.098 us; speedup 1.0000x reference)
//
#include <hip/hip_runtime.h>
#include <stdint.h>

// SelfAttention: B=4, S=4096, D=768, causal, fp32 in/out, bf16 MFMA compute.
// Decomposition: cvt -> qkv GEMM -> scores GEMM (+exp epilogue, packed causal
// P tiles) -> PV GEMM (/l epilogue). All GEMMs: 128x128 tile, 256 thr,
// 4 blocks/CU, BK=32 2-PHASE double-buffer: stage(t+1) issued BEFORE
// compute(t), single __syncthreads per step (drain lands AFTER the MFMAs, so
// gload latency hides under reads+MFMA). XOR chunk-swizzle staging (T2),
// global_load_lds width-16, XCD-bijective tile order on scores (T1, round 5).
// NOTE (rounds 1-4): 256^2-tile counted-vmcnt / m201 8-phase ports all
// measured ~11-12 CU-us per 128^2-tile (same as 2-barrier) -- do not revisit
// without disasm. launch_bounds min-waves beyond VGPR budget spills acc
// (round 2: 2.5 GB scratch). Numerics: MFMA k-order unchanged everywhere.
// ws layout (bf16 elements):
//   qb  12582912 @ 0
//   kb  12582912 @ 12582912
//   vt  12582912 @ 25165824   [b][e][s] (V transposed)
//   xb  12582912 @ 37748736   (dead after qkv_proj)
//   wb   1769472 @ 50331648   (dead after qkv_proj)
//   pb  34603008 @ 37748736   ALIAS over xb/wb: packed causal P tiles,
//                             tile (b, mt, nt<=mt) at slot b*528+mt(mt+1)/2+nt
//   ls  16384 fp32 @ elem 72351744
#define SEQ 4096
#define DIM 768

typedef __attribute__((ext_vector_type(8))) short short8;
typedef __attribute__((ext_vector_type(8))) unsigned short ushort8;
typedef __attribute__((ext_vector_type(4))) unsigned short ushort4v;
typedef __attribute__((ext_vector_type(4))) float fx4;
typedef unsigned short ushort;

#define MFMA16(a, b, c) __builtin_amdgcn_mfma_f32_16x16x32_bf16((a), (b), (c), 0, 0, 0)

__device__ __forceinline__ ushort f2bf(float f) {
  union { float f; unsigned int u; } v; v.f = f;
  return (ushort)((v.u + 0x7fffu + ((v.u >> 16) & 1u)) >> 16);
}
__device__ __forceinline__ float bf2f(ushort u) {
  union { unsigned int u; float f; } v; v.u = ((unsigned int)u) << 16;
  return v.f;
}
__device__ __forceinline__ void gload_lds16(const ushort* g, ushort* l) {
  __builtin_amdgcn_global_load_lds(
      (const __attribute__((address_space(1))) void*)g,
      (__attribute__((address_space(3))) void*)l, 16, 0, 0);
}

// ---------- kernel 0: fused fp32->bf16 casts + ls zero ----------
__global__ void cvt_all(const float* __restrict__ x, const float* __restrict__ wq,
                        const float* __restrict__ wk, const float* __restrict__ wv,
                        ushort* __restrict__ xb, ushort* __restrict__ wb,
                        float* __restrict__ ls) {
  const int bid = blockIdx.x;
  if (bid < 6144) {
    if (bid < 64) ls[bid * 256 + threadIdx.x] = 0.0f;
    const int i = (bid * 256 + threadIdx.x) * 8;
    fx4 a = *(const fx4*)(x + i);
    fx4 b = *(const fx4*)(x + i + 4);
    ushort8 o;
#pragma unroll
    for (int c = 0; c < 4; c++) { o[c] = f2bf(a[c]); o[c + 4] = f2bf(b[c]); }
    *(ushort8*)(xb + i) = o;
  } else {
    const int i = ((bid - 6144) * 256 + threadIdx.x) * 8;
    const int which = i / (DIM * DIM);
    const int off = i - which * (DIM * DIM);
    const float* src = (which == 0) ? wq : (which == 1) ? wk : wv;
    fx4 a = *(const fx4*)(src + off);
    fx4 b = *(const fx4*)(src + off + 4);
    ushort8 o;
#pragma unroll
    for (int c = 0; c < 4; c++) { o[c] = f2bf(a[c]); o[c + 4] = f2bf(b[c]); }
    *(ushort8*)(wb + i) = o;
  }
}

// ---------- kernel 1: QKV projection (128x128 tile, BK=32 2-phase) ----------
__global__ __launch_bounds__(256, 4)
void qkv_proj(const ushort* __restrict__ xb, const ushort* __restrict__ wb,
              ushort* __restrict__ qb, ushort* __restrict__ kb,
              ushort* __restrict__ vt) {
  __shared__ ushort smem[17408];  // k-loop: 2 x (A 8KB | B 8KB); epi 128x136

  const int mb = blockIdx.x, nb = blockIdx.y;
  const int which = nb / 6;
  const int e0 = (nb % 6) * 128;
  const int m0 = mb * 128;
  const int tid = threadIdx.x;
  const int w = tid >> 6, lane = tid & 63, ln = lane & 15, quad = lane >> 4;
  const int wm = (w >> 1) * 64, wn = (w & 1) * 64;
  const int w1024 = w * 1024;

  const ushort* W = wb + (size_t)which * (DIM * DIM);

  // per-panel staging: chunk c -> row R=c>>2, k-group kl=(c&3)^((R>>1)&3)
  const int c0 = w * 128 + lane;
  const int c1 = c0 + 64;
  const int R0 = c0 >> 2, kl0 = (c0 & 3) ^ ((R0 >> 1) & 3);
  const int R1 = c1 >> 2, kl1 = (c1 & 3) ^ ((R1 >> 1) & 3);
  const ushort* ag0 = xb + (size_t)(m0 + R0) * DIM + kl0 * 8;
  const ushort* ag1 = xb + (size_t)(m0 + R1) * DIM + kl1 * 8;
  const ushort* bg0 = W + (size_t)(e0 + R0) * DIM + kl0 * 8;
  const ushort* bg1 = W + (size_t)(e0 + R1) * DIM + kl1 * 8;

  const int sw = quad ^ ((ln >> 1) & 3);
  int aoff[4], boff[4];
#pragma unroll
  for (int i = 0; i < 4; i++) aoff[i] = ((wm + i * 16 + ln) * 4 + sw) * 8;
#pragma unroll
  for (int i = 0; i < 4; i++) boff[i] = ((wn + i * 16 + ln) * 4 + sw) * 8;

  fx4 acc[4][4];
#pragma unroll
  for (int i = 0; i < 4; i++)
#pragma unroll
    for (int j = 0; j < 4; j++) acc[i][j] = (fx4)0.0f;

#define STG32(BUF, KK) do {                                 \
    ushort* A_ = smem + (BUF) * 8192;                       \
    gload_lds16(ag0 + (KK), A_ + w1024);                    \
    gload_lds16(ag1 + (KK), A_ + w1024 + 512);              \
    gload_lds16(bg0 + (KK), A_ + 4096 + w1024);             \
    gload_lds16(bg1 + (KK), A_ + 4096 + w1024 + 512);       \
  } while (0)

  STG32(0, 0);
  __syncthreads();
  for (int t = 0; t < 24; ++t) {  // 768/32 k-steps
    if (t < 23) STG32((t + 1) & 1, (t + 1) * 32);
    const int bb = (t & 1) * 8192;
    short8 af[4], bf[4];
#pragma unroll
    for (int i = 0; i < 4; i++) af[i] = *(const short8*)(smem + bb + aoff[i]);
#pragma unroll
    for (int i = 0; i < 4; i++)
      bf[i] = *(const short8*)(smem + bb + 4096 + boff[i]);
#pragma unroll
    for (int i = 0; i < 4; i++)
#pragma unroll
      for (int j = 0; j < 4; j++)
        acc[i][j] = MFMA16(af[i], bf[j], acc[i][j]);
    __syncthreads();
  }
#undef STG32

  if (which == 2) {
#pragma unroll
    for (int i = 0; i < 4; i++)
#pragma unroll
      for (int j = 0; j < 4; j++) {
        const int s = m0 + wm + i * 16 + quad * 4;
        const int e = e0 + wn + j * 16 + ln;
        const int bb = s >> 12, si = s & 4095;
        ushort4v p;
#pragma unroll
        for (int r = 0; r < 4; r++) p[r] = f2bf(acc[i][j][r]);
        *(ushort4v*)(vt + ((size_t)bb * DIM + e) * SEQ + si) = p;
      }
  } else {
#pragma unroll
    for (int i = 0; i < 4; i++)
#pragma unroll
      for (int j = 0; j < 4; j++)
#pragma unroll
        for (int r = 0; r < 4; r++)
          smem[(wm + i * 16 + quad * 4 + r) * 136 + wn + j * 16 + ln] =
              f2bf(acc[i][j][r]);
    __syncthreads();
    ushort* dst = (which == 0) ? qb : kb;
#pragma unroll
    for (int p = 0; p < 8; p++) {
      const int tt = p * 256 + tid;
      const int row = tt >> 4, col = (tt & 15) * 8;
      ushort8 v = *(const ushort8*)&smem[row * 136 + col];
      *(ushort8*)(dst + (size_t)(m0 + row) * DIM + e0 + col) = v;
    }
  }
}

// ---------- kernel 2: scores GEMM + exp epilogue (BK=32 2-phase) ----------
__global__ __launch_bounds__(256, 4)
void attn_scores(const ushort* __restrict__ qb, const ushort* __restrict__ kb,
                 ushort* __restrict__ pb, float* __restrict__ ls) {
  __shared__ ushort smem[17408];

  // XCD-bijective tile order: 528 = 8*66 (round 5, measured -9us): each XCD
  // gets 66 consecutive triangle tiles -> Q/K panel reuse in its L2.
  const int x0 = blockIdx.x;
  const int pr = (x0 & 7) * 66 + (x0 >> 3);
  const int b = blockIdx.y;
  int mt = (int)(0.5f * (sqrtf(8.0f * pr + 1.0f) - 1.0f));
  while ((mt + 1) * (mt + 2) / 2 <= pr) ++mt;
  while (mt * (mt + 1) / 2 > pr) --mt;
  const int nt = pr - mt * (mt + 1) / 2;
  const int m0 = mt * 128, n0 = nt * 128;

  const int tid = threadIdx.x;
  const int w = tid >> 6, lane = tid & 63, ln = lane & 15, quad = lane >> 4;
  const int wm = (w >> 1) * 64, wn = (w & 1) * 64;
  const int w1024 = w * 1024;
  const size_t qkbase = (size_t)b * SEQ * DIM;
  const float scale = 0.03608439182435161f;  // 1/sqrt(768)

  const int c0 = w * 128 + lane;
  const int c1 = c0 + 64;
  const int R0 = c0 >> 2, kl0 = (c0 & 3) ^ ((R0 >> 1) & 3);
  const int R1 = c1 >> 2, kl1 = (c1 & 3) ^ ((R1 >> 1) & 3);
  const ushort* ag0 = qb + qkbase + (size_t)(m0 + R0) * DIM + kl0 * 8;
  const ushort* ag1 = qb + qkbase + (size_t)(m0 + R1) * DIM + kl1 * 8;
  const ushort* bg0 = kb + qkbase + (size_t)(n0 + R0) * DIM + kl0 * 8;
  const ushort* bg1 = kb + qkbase + (size_t)(n0 + R1) * DIM + kl1 * 8;

  const int sw = quad ^ ((ln >> 1) & 3);
  int aoff[4], boff[4];
#pragma unroll
  for (int i = 0; i < 4; i++) aoff[i] = ((wm + i * 16 + ln) * 4 + sw) * 8;
#pragma unroll
  for (int i = 0; i < 4; i++) boff[i] = ((wn + i * 16 + ln) * 4 + sw) * 8;

  fx4 acc[4][4];
#pragma unroll
  for (int i = 0; i < 4; i++)
#pragma unroll
    for (int j = 0; j < 4; j++) acc[i][j] = (fx4)0.0f;

#define STG32(BUF, KK) do {                                 \
    ushort* A_ = smem + (BUF) * 8192;                       \
    gload_lds16(ag0 + (KK), A_ + w1024);                    \
    gload_lds16(ag1 + (KK), A_ + w1024 + 512);              \
    gload_lds16(bg0 + (KK), A_ + 4096 + w1024);             \
    gload_lds16(bg1 + (KK), A_ + 4096 + w1024 + 512);       \
  } while (0)

  STG32(0, 0);
  __syncthreads();
  for (int t = 0; t < 24; ++t) {
    if (t < 23) STG32((t + 1) & 1, (t + 1) * 32);
    const int bb = (t & 1) * 8192;
    short8 af[4], bf[4];
#pragma unroll
    for (int i = 0; i < 4; i++) af[i] = *(const short8*)(smem + bb + aoff[i]);
#pragma unroll
    for (int i = 0; i < 4; i++)
      bf[i] = *(const short8*)(smem + bb + 4096 + boff[i]);
#pragma unroll
    for (int i = 0; i < 4; i++)
#pragma unroll
      for (int j = 0; j < 4; j++)
        acc[i][j] = MFMA16(af[i], bf[j], acc[i][j]);
    __syncthreads();
  }
#undef STG32

  // epilogue: exp + causal mask + row sums + pack via LDS
  float rowp[4][4];
#pragma unroll
  for (int i = 0; i < 4; i++) {
#pragma unroll
    for (int r = 0; r < 4; r++) rowp[i][r] = 0.0f;
#pragma unroll
    for (int j = 0; j < 4; j++) {
      const int col = n0 + wn + j * 16 + ln;
#pragma unroll
      for (int r = 0; r < 4; r++) {
        const int row = m0 + wm + i * 16 + quad * 4 + r;
        float p = 0.0f;
        if (col <= row) p = __expf(acc[i][j][r] * scale);
        const ushort pk = f2bf(p);
        smem[(wm + i * 16 + quad * 4 + r) * 136 + wn + j * 16 + ln] = pk;
        rowp[i][r] += bf2f(pk);
      }
    }
  }
#pragma unroll
  for (int i = 0; i < 4; i++)
#pragma unroll
    for (int r = 0; r < 4; r++) {
      float s = rowp[i][r];
      s += __shfl_xor(s, 1);
      s += __shfl_xor(s, 2);
      s += __shfl_xor(s, 4);
      s += __shfl_xor(s, 8);
      if (ln == 0)
        atomicAdd(ls + b * SEQ + m0 + wm + i * 16 + quad * 4 + r, s);
    }
  __syncthreads();
  ushort* pt = pb + ((size_t)(b * 528 + pr) << 14);
#pragma unroll
  for (int p = 0; p < 8; p++) {
    const int tt = p * 256 + tid;
    const int row = tt >> 4, col = (tt & 15) * 8;
    ushort8 v = *(const ushort8*)&smem[row * 136 + col];
    *(ushort8*)(pt + row * 128 + col) = v;
  }
}

// ---------- kernel 3: O = P_hat @ V, /l (BK=32 2-phase, serpentine) --------
__global__ __launch_bounds__(256, 4)
void attn_pv(const ushort* __restrict__ pb, const ushort* __restrict__ vt,
             const float* __restrict__ ls, float* __restrict__ out) {
  __shared__ ushort smem[16384];  // 2 x (A 8KB | B 8KB)

  // serpentine rank -> (mt desc, et, b): balances per-CU work at 3 blocks/CU
  int idx = blockIdx.x;
  int chunk = idx >> 8, pos = idx & 255;
  if (chunk & 1) pos = 255 - pos;
  const int r_ = (chunk << 8) + pos;
  const int mt = 31 - r_ / 24;
  const int rem = r_ % 24;
  const int b = rem & 3;
  const int et = rem >> 2;
  const int m0 = mt * 128, e0 = et * 128;

  const int tid = threadIdx.x;
  const int w = tid >> 6, lane = tid & 63, ln = lane & 15, quad = lane >> 4;
  const int wm = (w >> 1) * 64, wn = (w & 1) * 64;
  const int w1024 = w * 1024;
  const size_t vtbase = (size_t)b * DIM * SEQ;
  const ushort* ptiles = pb + ((size_t)(b * 528 + mt * (mt + 1) / 2) << 14);

  const int c0 = w * 128 + lane;
  const int c1 = c0 + 64;
  const int R0 = c0 >> 2, kl0 = (c0 & 3) ^ ((R0 >> 1) & 3);
  const int R1 = c1 >> 2, kl1 = (c1 & 3) ^ ((R1 >> 1) & 3);
  const ushort* ag0 = ptiles + R0 * 128 + kl0 * 8;
  const ushort* ag1 = ptiles + R1 * 128 + kl1 * 8;
  const ushort* bg0 = vt + vtbase + (size_t)(e0 + R0) * SEQ + kl0 * 8;
  const ushort* bg1 = vt + vtbase + (size_t)(e0 + R1) * SEQ + kl1 * 8;

  const int sw = quad ^ ((ln >> 1) & 3);
  int aoff[4], boff[4];
#pragma unroll
  for (int i = 0; i < 4; i++) aoff[i] = ((wm + i * 16 + ln) * 4 + sw) * 8;
#pragma unroll
  for (int i = 0; i < 4; i++) boff[i] = ((wn + i * 16 + ln) * 4 + sw) * 8;

  fx4 acc[4][4];
#pragma unroll
  for (int i = 0; i < 4; i++)
#pragma unroll
    for (int j = 0; j < 4; j++) acc[i][j] = (fx4)0.0f;

  // 32-wide k-step s: A src = ntile*16384 + (s&3)*32, B src = ntile*128+(s&3)*32
#define PSTG(BUF, S) do {                                   \
    const int nt_ = (S) >> 2, ki_ = ((S) & 3) * 32;         \
    const size_t ao_ = (size_t)nt_ * 16384 + ki_;           \
    const int bo_ = nt_ * 128 + ki_;                        \
    ushort* A_ = smem + (BUF) * 8192;                       \
    gload_lds16(ag0 + ao_, A_ + w1024);                     \
    gload_lds16(ag1 + ao_, A_ + w1024 + 512);               \
    gload_lds16(bg0 + bo_, A_ + 4096 + w1024);              \
    gload_lds16(bg1 + bo_, A_ + 4096 + w1024 + 512);        \
  } while (0)

  const int nk2 = (mt + 1) * 4;  // 32-wide k-steps
  PSTG(0, 0);
  __syncthreads();
  for (int s = 0; s < nk2; ++s) {
    if (s + 1 < nk2) PSTG((s + 1) & 1, s + 1);
    const int bb = (s & 1) * 8192;
    short8 af[4], bf[4];
#pragma unroll
    for (int i = 0; i < 4; i++) af[i] = *(const short8*)(smem + bb + aoff[i]);
#pragma unroll
    for (int i = 0; i < 4; i++)
      bf[i] = *(const short8*)(smem + bb + 4096 + boff[i]);
#pragma unroll
    for (int i = 0; i < 4; i++)
#pragma unroll
      for (int j = 0; j < 4; j++)
        acc[i][j] = MFMA16(af[i], bf[j], acc[i][j]);
    __syncthreads();
  }
#undef PSTG

#pragma unroll
  for (int i = 0; i < 4; i++)
#pragma unroll
    for (int r = 0; r < 4; r++) {
      const int row = m0 + wm + i * 16 + quad * 4 + r;
      const float linv = 1.0f / ls[b * SEQ + row];
      float* orow = out + ((size_t)(b * SEQ + row)) * DIM + e0 + wn + ln;
#pragma unroll
      for (int j = 0; j < 4; j++) orow[j * 16] = acc[i][j][r] * linv;
    }
}

extern "C" void kernel_launch(void* const* d_in, const int* in_sizes, int n_in,
                              void* d_out, int out_size, void* d_ws, size_t ws_size,
                              hipStream_t stream) {
  const float* x = (const float*)d_in[0];
  const float* wq = (const float*)d_in[1];
  const float* wk = (const float*)d_in[2];
  const float* wv = (const float*)d_in[3];
  float* out = (float*)d_out;

  ushort* qb = (ushort*)d_ws;
  ushort* kb = qb + 12582912;
  ushort* vt = kb + 12582912;
  ushort* xb = vt + 12582912;
  ushort* wb = xb + 12582912;
  ushort* pb = xb;  // alias: xb/wb dead after qkv_proj
  float* ls = (float*)((ushort*)d_ws + 72351744);

  cvt_all<<<7008, 256, 0, stream>>>(x, wq, wk, wv, xb, wb, ls);
  qkv_proj<<<dim3(128, 18), 256, 0, stream>>>(xb, wb, qb, kb, vt);
  attn_scores<<<dim3(528, 4), 256, 0, stream>>>(qb, kb, pb, ls);
  attn_pv<<<768, 256, 0, stream>>>(pb, vt, ls, out);
}

// Round 7
// 339.562 us; speedup vs baseline: 1.0369x; 1.0369x over previous
//
#include <hip/hip_runtime.h>
#include <stdint.h>

// SelfAttention: B=4, S=4096, D=768, causal, fp32 in/out, bf16 MFMA compute.
// Decomposition: cvt -> qkv GEMM -> scores GEMM (+exp epilogue, packed causal
// P tiles) -> PV GEMM (/l epilogue). All GEMMs: 128x128 tile, BK=64 (two
// BK=32 XOR-swizzled panels per barrier pair), global_load_lds width-16.
// T1 XCD-bijective remaps (round 5/7): scores 528=8*66 triangle chunks;
// qkv 2304=8*(16mb x 18nb) -> xb panels L2-local; pv work-balanced row pairs
// (2k,31-2k),(2k+1,30-2k) -> P-rows XCD-local, 66 tile-units per XCD exact.
// NOTE (rounds 1-4,6 post-mortems): 256^2 counted-vmcnt, m201 8-phase, and
// BK=32 early-issue 2-phase ALL measured at or below this 2-barrier
// structure (~11-12 CU-us per 128^2x768 tile). Do not revisit schedule
// structure without disasm. launch_bounds min-waves beyond VGPR budget
// spills acc (round 2: 2.5 GB scratch). MFMA k-order fixed everywhere.
// ws layout (bf16 elements):
//   qb  12582912 @ 0
//   kb  12582912 @ 12582912
//   vt  12582912 @ 25165824   [b][e][s] (V transposed)
//   xb  12582912 @ 37748736   (dead after qkv_proj)
//   wb   1769472 @ 50331648   (dead after qkv_proj)
//   pb  34603008 @ 37748736   ALIAS over xb/wb: packed causal P tiles,
//                             tile (b, mt, nt<=mt) at slot b*528+mt(mt+1)/2+nt
//   ls  16384 fp32 @ elem 72351744
#define SEQ 4096
#define DIM 768

typedef __attribute__((ext_vector_type(8))) short short8;
typedef __attribute__((ext_vector_type(8))) unsigned short ushort8;
typedef __attribute__((ext_vector_type(4))) unsigned short ushort4v;
typedef __attribute__((ext_vector_type(4))) float fx4;
typedef unsigned short ushort;

#define MFMA16(a, b, c) __builtin_amdgcn_mfma_f32_16x16x32_bf16((a), (b), (c), 0, 0, 0)

__device__ __forceinline__ ushort f2bf(float f) {
  union { float f; unsigned int u; } v; v.f = f;
  return (ushort)((v.u + 0x7fffu + ((v.u >> 16) & 1u)) >> 16);
}
__device__ __forceinline__ float bf2f(ushort u) {
  union { unsigned int u; float f; } v; v.u = ((unsigned int)u) << 16;
  return v.f;
}
__device__ __forceinline__ void gload_lds16(const ushort* g, ushort* l) {
  __builtin_amdgcn_global_load_lds(
      (const __attribute__((address_space(1))) void*)g,
      (__attribute__((address_space(3))) void*)l, 16, 0, 0);
}

// ---------- kernel 0: fused fp32->bf16 casts + ls zero ----------
__global__ void cvt_all(const float* __restrict__ x, const float* __restrict__ wq,
                        const float* __restrict__ wk, const float* __restrict__ wv,
                        ushort* __restrict__ xb, ushort* __restrict__ wb,
                        float* __restrict__ ls) {
  const int bid = blockIdx.x;
  if (bid < 6144) {
    if (bid < 64) ls[bid * 256 + threadIdx.x] = 0.0f;
    const int i = (bid * 256 + threadIdx.x) * 8;
    fx4 a = *(const fx4*)(x + i);
    fx4 b = *(const fx4*)(x + i + 4);
    ushort8 o;
#pragma unroll
    for (int c = 0; c < 4; c++) { o[c] = f2bf(a[c]); o[c + 4] = f2bf(b[c]); }
    *(ushort8*)(xb + i) = o;
  } else {
    const int i = ((bid - 6144) * 256 + threadIdx.x) * 8;
    const int which = i / (DIM * DIM);
    const int off = i - which * (DIM * DIM);
    const float* src = (which == 0) ? wq : (which == 1) ? wk : wv;
    fx4 a = *(const fx4*)(src + off);
    fx4 b = *(const fx4*)(src + off + 4);
    ushort8 o;
#pragma unroll
    for (int c = 0; c < 4; c++) { o[c] = f2bf(a[c]); o[c + 4] = f2bf(b[c]); }
    *(ushort8*)(wb + i) = o;
  }
}

// ---------- kernel 1: QKV projection (128x128 tile, BK=64) ----------
// 2304 blocks = 8 XCDs x (16 mb x 18 nb): each XCD owns 16 contiguous mb
// rows (3 MB of xb, L2-resident) reused across all 18 weight panels.
__global__ __launch_bounds__(256, 4)
void qkv_proj(const ushort* __restrict__ xb, const ushort* __restrict__ wb,
              ushort* __restrict__ qb, ushort* __restrict__ kb,
              ushort* __restrict__ vt) {
  __shared__ ushort smem[17408];  // k-loop: As[8192]|Bs[8192]; epilogue 128x136
  ushort* As = smem;
  ushort* Bs = smem + 8192;

  const int lin = blockIdx.x;
  const int xcd = lin & 7;
  const int idx = lin >> 3;           // 0..287
  const int mb = xcd * 16 + (idx & 15);
  const int nb = idx >> 4;            // 0..17
  const int which = nb / 6;
  const int e0 = (nb % 6) * 128;
  const int m0 = mb * 128;
  const int tid = threadIdx.x;
  const int w = tid >> 6, lane = tid & 63, ln = lane & 15, quad = lane >> 4;
  const int wm = (w >> 1) * 64, wn = (w & 1) * 64;

  const ushort* W = wb + (size_t)which * (DIM * DIM);

  // per-panel staging: chunk c -> row R=c>>2, k-group kl=(c&3)^((R>>1)&3)
  const int c0 = w * 128 + lane;
  const int c1 = c0 + 64;
  const int R0 = c0 >> 2, kl0 = (c0 & 3) ^ ((R0 >> 1) & 3);
  const int R1 = c1 >> 2, kl1 = (c1 & 3) ^ ((R1 >> 1) & 3);
  const ushort* ag0 = xb + (size_t)(m0 + R0) * DIM + kl0 * 8;
  const ushort* ag1 = xb + (size_t)(m0 + R1) * DIM + kl1 * 8;
  const ushort* bg0 = W + (size_t)(e0 + R0) * DIM + kl0 * 8;
  const ushort* bg1 = W + (size_t)(e0 + R1) * DIM + kl1 * 8;
  ushort* al0 = As + (size_t)(w * 128) * 8;
  ushort* al1 = As + (size_t)(w * 128 + 64) * 8;
  ushort* bl0 = Bs + (size_t)(w * 128) * 8;
  ushort* bl1 = Bs + (size_t)(w * 128 + 64) * 8;

  const int sw = quad ^ ((ln >> 1) & 3);
  int aoff[4], boff[4];
#pragma unroll
  for (int i = 0; i < 4; i++) aoff[i] = ((wm + i * 16 + ln) * 4 + sw) * 8;
#pragma unroll
  for (int i = 0; i < 4; i++) boff[i] = ((wn + i * 16 + ln) * 4 + sw) * 8;

  fx4 acc[4][4];
#pragma unroll
  for (int i = 0; i < 4; i++)
#pragma unroll
    for (int j = 0; j < 4; j++) acc[i][j] = (fx4)0.0f;

  for (int kk = 0; kk < DIM; kk += 64) {
    gload_lds16(ag0 + kk, al0);
    gload_lds16(ag1 + kk, al1);
    gload_lds16(ag0 + kk + 32, al0 + 4096);
    gload_lds16(ag1 + kk + 32, al1 + 4096);
    gload_lds16(bg0 + kk, bl0);
    gload_lds16(bg1 + kk, bl1);
    gload_lds16(bg0 + kk + 32, bl0 + 4096);
    gload_lds16(bg1 + kk + 32, bl1 + 4096);
    __syncthreads();
#pragma unroll
    for (int h = 0; h < 2; h++) {
      const int hb = h * 4096;
      short8 af[4], bf[4];
#pragma unroll
      for (int i = 0; i < 4; i++) af[i] = *(const short8*)(As + hb + aoff[i]);
#pragma unroll
      for (int i = 0; i < 4; i++) bf[i] = *(const short8*)(Bs + hb + boff[i]);
#pragma unroll
      for (int i = 0; i < 4; i++)
#pragma unroll
        for (int j = 0; j < 4; j++)
          acc[i][j] = MFMA16(af[i], bf[j], acc[i][j]);
    }
    __syncthreads();
  }

  if (which == 2) {
#pragma unroll
    for (int i = 0; i < 4; i++)
#pragma unroll
      for (int j = 0; j < 4; j++) {
        const int s = m0 + wm + i * 16 + quad * 4;
        const int e = e0 + wn + j * 16 + ln;
        const int bb = s >> 12, si = s & 4095;
        ushort4v p;
#pragma unroll
        for (int r = 0; r < 4; r++) p[r] = f2bf(acc[i][j][r]);
        *(ushort4v*)(vt + ((size_t)bb * DIM + e) * SEQ + si) = p;
      }
  } else {
#pragma unroll
    for (int i = 0; i < 4; i++)
#pragma unroll
      for (int j = 0; j < 4; j++)
#pragma unroll
        for (int r = 0; r < 4; r++)
          smem[(wm + i * 16 + quad * 4 + r) * 136 + wn + j * 16 + ln] =
              f2bf(acc[i][j][r]);
    __syncthreads();
    ushort* dst = (which == 0) ? qb : kb;
#pragma unroll
    for (int p = 0; p < 8; p++) {
      const int tt = p * 256 + tid;
      const int row = tt >> 4, col = (tt & 15) * 8;
      ushort8 v = *(const ushort8*)&smem[row * 136 + col];
      *(ushort8*)(dst + (size_t)(m0 + row) * DIM + e0 + col) = v;
    }
  }
}

// ---------- kernel 2: scores GEMM + exp epilogue (BK=64) ----------
__global__ __launch_bounds__(256, 4)
void attn_scores(const ushort* __restrict__ qb, const ushort* __restrict__ kb,
                 ushort* __restrict__ pb, float* __restrict__ ls) {
  __shared__ ushort smem[17408];
  ushort* As = smem;
  ushort* Bs = smem + 8192;

  // XCD-bijective tile order: 528 = 8*66 (round 5, measured -9us): each XCD
  // gets 66 consecutive triangle tiles -> Q/K panel reuse in its L2.
  const int x0 = blockIdx.x;
  const int pr = (x0 & 7) * 66 + (x0 >> 3);
  const int b = blockIdx.y;
  int mt = (int)(0.5f * (sqrtf(8.0f * pr + 1.0f) - 1.0f));
  while ((mt + 1) * (mt + 2) / 2 <= pr) ++mt;
  while (mt * (mt + 1) / 2 > pr) --mt;
  const int nt = pr - mt * (mt + 1) / 2;
  const int m0 = mt * 128, n0 = nt * 128;

  const int tid = threadIdx.x;
  const int w = tid >> 6, lane = tid & 63, ln = lane & 15, quad = lane >> 4;
  const int wm = (w >> 1) * 64, wn = (w & 1) * 64;
  const size_t qkbase = (size_t)b * SEQ * DIM;
  const float scale = 0.03608439182435161f;  // 1/sqrt(768)

  const int c0 = w * 128 + lane;
  const int c1 = c0 + 64;
  const int R0 = c0 >> 2, kl0 = (c0 & 3) ^ ((R0 >> 1) & 3);
  const int R1 = c1 >> 2, kl1 = (c1 & 3) ^ ((R1 >> 1) & 3);
  const ushort* ag0 = qb + qkbase + (size_t)(m0 + R0) * DIM + kl0 * 8;
  const ushort* ag1 = qb + qkbase + (size_t)(m0 + R1) * DIM + kl1 * 8;
  const ushort* bg0 = kb + qkbase + (size_t)(n0 + R0) * DIM + kl0 * 8;
  const ushort* bg1 = kb + qkbase + (size_t)(n0 + R1) * DIM + kl1 * 8;
  ushort* al0 = As + (size_t)(w * 128) * 8;
  ushort* al1 = As + (size_t)(w * 128 + 64) * 8;
  ushort* bl0 = Bs + (size_t)(w * 128) * 8;
  ushort* bl1 = Bs + (size_t)(w * 128 + 64) * 8;

  const int sw = quad ^ ((ln >> 1) & 3);
  int aoff[4], boff[4];
#pragma unroll
  for (int i = 0; i < 4; i++) aoff[i] = ((wm + i * 16 + ln) * 4 + sw) * 8;
#pragma unroll
  for (int i = 0; i < 4; i++) boff[i] = ((wn + i * 16 + ln) * 4 + sw) * 8;

  fx4 acc[4][4];
#pragma unroll
  for (int i = 0; i < 4; i++)
#pragma unroll
    for (int j = 0; j < 4; j++) acc[i][j] = (fx4)0.0f;

  for (int kk = 0; kk < DIM; kk += 64) {
    gload_lds16(ag0 + kk, al0);
    gload_lds16(ag1 + kk, al1);
    gload_lds16(ag0 + kk + 32, al0 + 4096);
    gload_lds16(ag1 + kk + 32, al1 + 4096);
    gload_lds16(bg0 + kk, bl0);
    gload_lds16(bg1 + kk, bl1);
    gload_lds16(bg0 + kk + 32, bl0 + 4096);
    gload_lds16(bg1 + kk + 32, bl1 + 4096);
    __syncthreads();
#pragma unroll
    for (int h = 0; h < 2; h++) {
      const int hb = h * 4096;
      short8 af[4], bf[4];
#pragma unroll
      for (int i = 0; i < 4; i++) af[i] = *(const short8*)(As + hb + aoff[i]);
#pragma unroll
      for (int i = 0; i < 4; i++) bf[i] = *(const short8*)(Bs + hb + boff[i]);
#pragma unroll
      for (int i = 0; i < 4; i++)
#pragma unroll
        for (int j = 0; j < 4; j++)
          acc[i][j] = MFMA16(af[i], bf[j], acc[i][j]);
    }
    __syncthreads();
  }

  // epilogue: exp + causal mask + row sums + pack via LDS
  float rowp[4][4];
#pragma unroll
  for (int i = 0; i < 4; i++) {
#pragma unroll
    for (int r = 0; r < 4; r++) rowp[i][r] = 0.0f;
#pragma unroll
    for (int j = 0; j < 4; j++) {
      const int col = n0 + wn + j * 16 + ln;
#pragma unroll
      for (int r = 0; r < 4; r++) {
        const int row = m0 + wm + i * 16 + quad * 4 + r;
        float p = 0.0f;
        if (col <= row) p = __expf(acc[i][j][r] * scale);
        const ushort pk = f2bf(p);
        smem[(wm + i * 16 + quad * 4 + r) * 136 + wn + j * 16 + ln] = pk;
        rowp[i][r] += bf2f(pk);
      }
    }
  }
#pragma unroll
  for (int i = 0; i < 4; i++)
#pragma unroll
    for (int r = 0; r < 4; r++) {
      float s = rowp[i][r];
      s += __shfl_xor(s, 1);
      s += __shfl_xor(s, 2);
      s += __shfl_xor(s, 4);
      s += __shfl_xor(s, 8);
      if (ln == 0)
        atomicAdd(ls + b * SEQ + m0 + wm + i * 16 + quad * 4 + r, s);
    }
  __syncthreads();
  ushort* pt = pb + ((size_t)(b * 528 + pr) << 14);
#pragma unroll
  for (int p = 0; p < 8; p++) {
    const int tt = p * 256 + tid;
    const int row = tt >> 4, col = (tt & 15) * 8;
    ushort8 v = *(const ushort8*)&smem[row * 136 + col];
    *(ushort8*)(pt + row * 128 + col) = v;
  }
}

// ---------- kernel 3: O = P_hat @ V, divide by l (BK=64) ----------
// XCD-balanced row pairing: XCD k owns mt rows {31-2k, 2k, 30-2k, 2k+1}
// (pairs sum to 33 tile-units -> exactly 66 per XCD; P-rows XCD-local,
// heavy/light interleaved for tail balance). 768 = 8 x 96 bijective.
__global__ __launch_bounds__(256, 4)
void attn_pv(const ushort* __restrict__ pb, const ushort* __restrict__ vt,
             const float* __restrict__ ls, float* __restrict__ out) {
  __shared__ ushort smem[16384];
  ushort* As = smem;
  ushort* Bs = smem + 8192;

  const int idx = blockIdx.x;       // 0..767
  const int xcd = idx & 7;
  const int pos = idx >> 3;         // 0..95
  const int slot = pos / 24;        // 0..3
  const int rem = pos % 24;
  const int b = rem & 3;
  const int et = rem >> 2;
  const int mt = (slot == 0) ? 31 - 2 * xcd
               : (slot == 1) ? 2 * xcd
               : (slot == 2) ? 30 - 2 * xcd
                             : 2 * xcd + 1;
  const int m0 = mt * 128, e0 = et * 128;

  const int tid = threadIdx.x;
  const int w = tid >> 6, lane = tid & 63, ln = lane & 15, quad = lane >> 4;
  const int wm = (w >> 1) * 64, wn = (w & 1) * 64;
  const size_t vtbase = (size_t)b * DIM * SEQ;
  const ushort* ptiles = pb + ((size_t)(b * 528 + mt * (mt + 1) / 2) << 14);

  const int c0 = w * 128 + lane;
  const int c1 = c0 + 64;
  const int R0 = c0 >> 2, kl0 = (c0 & 3) ^ ((R0 >> 1) & 3);
  const int R1 = c1 >> 2, kl1 = (c1 & 3) ^ ((R1 >> 1) & 3);
  const ushort* ag0 = ptiles + R0 * 128 + kl0 * 8;
  const ushort* ag1 = ptiles + R1 * 128 + kl1 * 8;
  const ushort* bg0 = vt + vtbase + (size_t)(e0 + R0) * SEQ + kl0 * 8;
  const ushort* bg1 = vt + vtbase + (size_t)(e0 + R1) * SEQ + kl1 * 8;
  ushort* al0 = As + (size_t)(w * 128) * 8;
  ushort* al1 = As + (size_t)(w * 128 + 64) * 8;
  ushort* bl0 = Bs + (size_t)(w * 128) * 8;
  ushort* bl1 = Bs + (size_t)(w * 128 + 64) * 8;

  const int sw = quad ^ ((ln >> 1) & 3);
  int aoff[4], boff[4];
#pragma unroll
  for (int i = 0; i < 4; i++) aoff[i] = ((wm + i * 16 + ln) * 4 + sw) * 8;
#pragma unroll
  for (int i = 0; i < 4; i++) boff[i] = ((wn + i * 16 + ln) * 4 + sw) * 8;

  fx4 acc[4][4];
#pragma unroll
  for (int i = 0; i < 4; i++)
#pragma unroll
    for (int j = 0; j < 4; j++) acc[i][j] = (fx4)0.0f;

  const int nk = (mt + 1) * 2;  // 64-wide k-steps
  for (int ks = 0; ks < nk; ks++) {
    const int ntile = ks >> 1;
    const int kin = (ks & 1) * 64;
    const size_t atile = (size_t)ntile * 16384 + kin;
    const int kglob = ntile * 128 + kin;
    gload_lds16(ag0 + atile, al0);
    gload_lds16(ag1 + atile, al1);
    gload_lds16(ag0 + atile + 32, al0 + 4096);
    gload_lds16(ag1 + atile + 32, al1 + 4096);
    gload_lds16(bg0 + kglob, bl0);
    gload_lds16(bg1 + kglob, bl1);
    gload_lds16(bg0 + kglob + 32, bl0 + 4096);
    gload_lds16(bg1 + kglob + 32, bl1 + 4096);
    __syncthreads();
#pragma unroll
    for (int h = 0; h < 2; h++) {
      const int hb = h * 4096;
      short8 af[4], bf[4];
#pragma unroll
      for (int i = 0; i < 4; i++) af[i] = *(const short8*)(As + hb + aoff[i]);
#pragma unroll
      for (int i = 0; i < 4; i++) bf[i] = *(const short8*)(Bs + hb + boff[i]);
#pragma unroll
      for (int i = 0; i < 4; i++)
#pragma unroll
        for (int j = 0; j < 4; j++)
          acc[i][j] = MFMA16(af[i], bf[j], acc[i][j]);
    }
    __syncthreads();
  }

#pragma unroll
  for (int i = 0; i < 4; i++)
#pragma unroll
    for (int r = 0; r < 4; r++) {
      const int row = m0 + wm + i * 16 + quad * 4 + r;
      const float linv = 1.0f / ls[b * SEQ + row];
      float* orow = out + ((size_t)(b * SEQ + row)) * DIM + e0 + wn + ln;
#pragma unroll
      for (int j = 0; j < 4; j++) orow[j * 16] = acc[i][j][r] * linv;
    }
}

extern "C" void kernel_launch(void* const* d_in, const int* in_sizes, int n_in,
                              void* d_out, int out_size, void* d_ws, size_t ws_size,
                              hipStream_t stream) {
  const float* x = (const float*)d_in[0];
  const float* wq = (const float*)d_in[1];
  const float* wk = (const float*)d_in[2];
  const float* wv = (const float*)d_in[3];
  float* out = (float*)d_out;

  ushort* qb = (ushort*)d_ws;
  ushort* kb = qb + 12582912;
  ushort* vt = kb + 12582912;
  ushort* xb = vt + 12582912;
  ushort* wb = xb + 12582912;
  ushort* pb = xb;  // alias: xb/wb dead after qkv_proj
  float* ls = (float*)((ushort*)d_ws + 72351744);

  cvt_all<<<7008, 256, 0, stream>>>(x, wq, wk, wv, xb, wb, ls);
  qkv_proj<<<2304, 256, 0, stream>>>(xb, wb, qb, kb, vt);
  attn_scores<<<dim3(528, 4), 256, 0, stream>>>(qb, kb, pb, ls);
  attn_pv<<<768, 256, 0, stream>>>(pb, vt, ls, out);
}

// Round 8
// 333.830 us; speedup vs baseline: 1.0547x; 1.0172x over previous
//
#include <hip/hip_runtime.h>
#include <stdint.h>

// SelfAttention: B=4, S=4096, D=768, causal, fp32 in/out, bf16 MFMA compute.
// Decomposition: cvt -> qkv GEMM -> scores GEMM (+exp epilogue, packed causal
// P tiles) -> PV GEMM (/l epilogue). All GEMMs: 128x128 tile, BK=64 (two
// BK=32 XOR-swizzled panels per barrier pair), global_load_lds width-16.
// Round-5 config == session best (330.4 us measured). Scores has the one
// verified T1 win: 528 = 8*66 XCD-bijective triangle chunks (-9 us, FETCH
// 234->~140 MB). qkv keeps (128,18) grid and pv keeps serpentine order:
// round-7 remaps of those two cost +9.2 us (qkv remap redundant -- mod-8
// dispatch already gives each XCD a fixed 3MB xb row set; pv pairing broke
// the serpentine's temporal balance at 3 blocks/CU).
// NOTE (rounds 1-4,6): 256^2 counted-vmcnt, m201 8-phase, and BK=32
// early-issue 2-phase ALL measured at or below this 2-barrier structure
// (~11-12 CU-us per 128^2x768 tile). Do not revisit schedule structure
// without disasm. launch_bounds min-waves beyond VGPR budget spills acc
// (round 2: 2.5 GB scratch). MFMA k-order fixed everywhere.
// ws layout (bf16 elements):
//   qb  12582912 @ 0
//   kb  12582912 @ 12582912
//   vt  12582912 @ 25165824   [b][e][s] (V transposed)
//   xb  12582912 @ 37748736   (dead after qkv_proj)
//   wb   1769472 @ 50331648   (dead after qkv_proj)
//   pb  34603008 @ 37748736   ALIAS over xb/wb: packed causal P tiles,
//                             tile (b, mt, nt<=mt) at slot b*528+mt(mt+1)/2+nt
//   ls  16384 fp32 @ elem 72351744
#define SEQ 4096
#define DIM 768

typedef __attribute__((ext_vector_type(8))) short short8;
typedef __attribute__((ext_vector_type(8))) unsigned short ushort8;
typedef __attribute__((ext_vector_type(4))) unsigned short ushort4v;
typedef __attribute__((ext_vector_type(4))) float fx4;
typedef unsigned short ushort;

#define MFMA16(a, b, c) __builtin_amdgcn_mfma_f32_16x16x32_bf16((a), (b), (c), 0, 0, 0)

__device__ __forceinline__ ushort f2bf(float f) {
  union { float f; unsigned int u; } v; v.f = f;
  return (ushort)((v.u + 0x7fffu + ((v.u >> 16) & 1u)) >> 16);
}
__device__ __forceinline__ float bf2f(ushort u) {
  union { unsigned int u; float f; } v; v.u = ((unsigned int)u) << 16;
  return v.f;
}
__device__ __forceinline__ void gload_lds16(const ushort* g, ushort* l) {
  __builtin_amdgcn_global_load_lds(
      (const __attribute__((address_space(1))) void*)g,
      (__attribute__((address_space(3))) void*)l, 16, 0, 0);
}

// ---------- kernel 0: fused fp32->bf16 casts + ls zero ----------
__global__ void cvt_all(const float* __restrict__ x, const float* __restrict__ wq,
                        const float* __restrict__ wk, const float* __restrict__ wv,
                        ushort* __restrict__ xb, ushort* __restrict__ wb,
                        float* __restrict__ ls) {
  const int bid = blockIdx.x;
  if (bid < 6144) {
    if (bid < 64) ls[bid * 256 + threadIdx.x] = 0.0f;
    const int i = (bid * 256 + threadIdx.x) * 8;
    fx4 a = *(const fx4*)(x + i);
    fx4 b = *(const fx4*)(x + i + 4);
    ushort8 o;
#pragma unroll
    for (int c = 0; c < 4; c++) { o[c] = f2bf(a[c]); o[c + 4] = f2bf(b[c]); }
    *(ushort8*)(xb + i) = o;
  } else {
    const int i = ((bid - 6144) * 256 + threadIdx.x) * 8;
    const int which = i / (DIM * DIM);
    const int off = i - which * (DIM * DIM);
    const float* src = (which == 0) ? wq : (which == 1) ? wk : wv;
    fx4 a = *(const fx4*)(src + off);
    fx4 b = *(const fx4*)(src + off + 4);
    ushort8 o;
#pragma unroll
    for (int c = 0; c < 4; c++) { o[c] = f2bf(a[c]); o[c + 4] = f2bf(b[c]); }
    *(ushort8*)(wb + i) = o;
  }
}

// ---------- kernel 1: QKV projection (128x128 tile, BK=64) ----------
__global__ __launch_bounds__(256, 4)
void qkv_proj(const ushort* __restrict__ xb, const ushort* __restrict__ wb,
              ushort* __restrict__ qb, ushort* __restrict__ kb,
              ushort* __restrict__ vt) {
  __shared__ ushort smem[17408];  // k-loop: As[8192]|Bs[8192]; epilogue 128x136
  ushort* As = smem;
  ushort* Bs = smem + 8192;

  const int mb = blockIdx.x, nb = blockIdx.y;
  const int which = nb / 6;
  const int e0 = (nb % 6) * 128;
  const int m0 = mb * 128;
  const int tid = threadIdx.x;
  const int w = tid >> 6, lane = tid & 63, ln = lane & 15, quad = lane >> 4;
  const int wm = (w >> 1) * 64, wn = (w & 1) * 64;

  const ushort* W = wb + (size_t)which * (DIM * DIM);

  // per-panel staging: chunk c -> row R=c>>2, k-group kl=(c&3)^((R>>1)&3)
  const int c0 = w * 128 + lane;
  const int c1 = c0 + 64;
  const int R0 = c0 >> 2, kl0 = (c0 & 3) ^ ((R0 >> 1) & 3);
  const int R1 = c1 >> 2, kl1 = (c1 & 3) ^ ((R1 >> 1) & 3);
  const ushort* ag0 = xb + (size_t)(m0 + R0) * DIM + kl0 * 8;
  const ushort* ag1 = xb + (size_t)(m0 + R1) * DIM + kl1 * 8;
  const ushort* bg0 = W + (size_t)(e0 + R0) * DIM + kl0 * 8;
  const ushort* bg1 = W + (size_t)(e0 + R1) * DIM + kl1 * 8;
  ushort* al0 = As + (size_t)(w * 128) * 8;
  ushort* al1 = As + (size_t)(w * 128 + 64) * 8;
  ushort* bl0 = Bs + (size_t)(w * 128) * 8;
  ushort* bl1 = Bs + (size_t)(w * 128 + 64) * 8;

  const int sw = quad ^ ((ln >> 1) & 3);
  int aoff[4], boff[4];
#pragma unroll
  for (int i = 0; i < 4; i++) aoff[i] = ((wm + i * 16 + ln) * 4 + sw) * 8;
#pragma unroll
  for (int i = 0; i < 4; i++) boff[i] = ((wn + i * 16 + ln) * 4 + sw) * 8;

  fx4 acc[4][4];
#pragma unroll
  for (int i = 0; i < 4; i++)
#pragma unroll
    for (int j = 0; j < 4; j++) acc[i][j] = (fx4)0.0f;

  for (int kk = 0; kk < DIM; kk += 64) {
    gload_lds16(ag0 + kk, al0);
    gload_lds16(ag1 + kk, al1);
    gload_lds16(ag0 + kk + 32, al0 + 4096);
    gload_lds16(ag1 + kk + 32, al1 + 4096);
    gload_lds16(bg0 + kk, bl0);
    gload_lds16(bg1 + kk, bl1);
    gload_lds16(bg0 + kk + 32, bl0 + 4096);
    gload_lds16(bg1 + kk + 32, bl1 + 4096);
    __syncthreads();
#pragma unroll
    for (int h = 0; h < 2; h++) {
      const int hb = h * 4096;
      short8 af[4], bf[4];
#pragma unroll
      for (int i = 0; i < 4; i++) af[i] = *(const short8*)(As + hb + aoff[i]);
#pragma unroll
      for (int i = 0; i < 4; i++) bf[i] = *(const short8*)(Bs + hb + boff[i]);
#pragma unroll
      for (int i = 0; i < 4; i++)
#pragma unroll
        for (int j = 0; j < 4; j++)
          acc[i][j] = MFMA16(af[i], bf[j], acc[i][j]);
    }
    __syncthreads();
  }

  if (which == 2) {
#pragma unroll
    for (int i = 0; i < 4; i++)
#pragma unroll
      for (int j = 0; j < 4; j++) {
        const int s = m0 + wm + i * 16 + quad * 4;
        const int e = e0 + wn + j * 16 + ln;
        const int bb = s >> 12, si = s & 4095;
        ushort4v p;
#pragma unroll
        for (int r = 0; r < 4; r++) p[r] = f2bf(acc[i][j][r]);
        *(ushort4v*)(vt + ((size_t)bb * DIM + e) * SEQ + si) = p;
      }
  } else {
#pragma unroll
    for (int i = 0; i < 4; i++)
#pragma unroll
      for (int j = 0; j < 4; j++)
#pragma unroll
        for (int r = 0; r < 4; r++)
          smem[(wm + i * 16 + quad * 4 + r) * 136 + wn + j * 16 + ln] =
              f2bf(acc[i][j][r]);
    __syncthreads();
    ushort* dst = (which == 0) ? qb : kb;
#pragma unroll
    for (int p = 0; p < 8; p++) {
      const int tt = p * 256 + tid;
      const int row = tt >> 4, col = (tt & 15) * 8;
      ushort8 v = *(const ushort8*)&smem[row * 136 + col];
      *(ushort8*)(dst + (size_t)(m0 + row) * DIM + e0 + col) = v;
    }
  }
}

// ---------- kernel 2: scores GEMM + exp epilogue (BK=64) ----------
__global__ __launch_bounds__(256, 4)
void attn_scores(const ushort* __restrict__ qb, const ushort* __restrict__ kb,
                 ushort* __restrict__ pb, float* __restrict__ ls) {
  __shared__ ushort smem[17408];
  ushort* As = smem;
  ushort* Bs = smem + 8192;

  // XCD-bijective tile order: 528 = 8*66 (round 5, measured -9us): each XCD
  // gets 66 consecutive triangle tiles -> Q/K panel reuse in its L2.
  const int x0 = blockIdx.x;
  const int pr = (x0 & 7) * 66 + (x0 >> 3);
  const int b = blockIdx.y;
  int mt = (int)(0.5f * (sqrtf(8.0f * pr + 1.0f) - 1.0f));
  while ((mt + 1) * (mt + 2) / 2 <= pr) ++mt;
  while (mt * (mt + 1) / 2 > pr) --mt;
  const int nt = pr - mt * (mt + 1) / 2;
  const int m0 = mt * 128, n0 = nt * 128;

  const int tid = threadIdx.x;
  const int w = tid >> 6, lane = tid & 63, ln = lane & 15, quad = lane >> 4;
  const int wm = (w >> 1) * 64, wn = (w & 1) * 64;
  const size_t qkbase = (size_t)b * SEQ * DIM;
  const float scale = 0.03608439182435161f;  // 1/sqrt(768)

  const int c0 = w * 128 + lane;
  const int c1 = c0 + 64;
  const int R0 = c0 >> 2, kl0 = (c0 & 3) ^ ((R0 >> 1) & 3);
  const int R1 = c1 >> 2, kl1 = (c1 & 3) ^ ((R1 >> 1) & 3);
  const ushort* ag0 = qb + qkbase + (size_t)(m0 + R0) * DIM + kl0 * 8;
  const ushort* ag1 = qb + qkbase + (size_t)(m0 + R1) * DIM + kl1 * 8;
  const ushort* bg0 = kb + qkbase + (size_t)(n0 + R0) * DIM + kl0 * 8;
  const ushort* bg1 = kb + qkbase + (size_t)(n0 + R1) * DIM + kl1 * 8;
  ushort* al0 = As + (size_t)(w * 128) * 8;
  ushort* al1 = As + (size_t)(w * 128 + 64) * 8;
  ushort* bl0 = Bs + (size_t)(w * 128) * 8;
  ushort* bl1 = Bs + (size_t)(w * 128 + 64) * 8;

  const int sw = quad ^ ((ln >> 1) & 3);
  int aoff[4], boff[4];
#pragma unroll
  for (int i = 0; i < 4; i++) aoff[i] = ((wm + i * 16 + ln) * 4 + sw) * 8;
#pragma unroll
  for (int i = 0; i < 4; i++) boff[i] = ((wn + i * 16 + ln) * 4 + sw) * 8;

  fx4 acc[4][4];
#pragma unroll
  for (int i = 0; i < 4; i++)
#pragma unroll
    for (int j = 0; j < 4; j++) acc[i][j] = (fx4)0.0f;

  for (int kk = 0; kk < DIM; kk += 64) {
    gload_lds16(ag0 + kk, al0);
    gload_lds16(ag1 + kk, al1);
    gload_lds16(ag0 + kk + 32, al0 + 4096);
    gload_lds16(ag1 + kk + 32, al1 + 4096);
    gload_lds16(bg0 + kk, bl0);
    gload_lds16(bg1 + kk, bl1);
    gload_lds16(bg0 + kk + 32, bl0 + 4096);
    gload_lds16(bg1 + kk + 32, bl1 + 4096);
    __syncthreads();
#pragma unroll
    for (int h = 0; h < 2; h++) {
      const int hb = h * 4096;
      short8 af[4], bf[4];
#pragma unroll
      for (int i = 0; i < 4; i++) af[i] = *(const short8*)(As + hb + aoff[i]);
#pragma unroll
      for (int i = 0; i < 4; i++) bf[i] = *(const short8*)(Bs + hb + boff[i]);
#pragma unroll
      for (int i = 0; i < 4; i++)
#pragma unroll
        for (int j = 0; j < 4; j++)
          acc[i][j] = MFMA16(af[i], bf[j], acc[i][j]);
    }
    __syncthreads();
  }

  // epilogue: exp + causal mask + row sums + pack via LDS
  float rowp[4][4];
#pragma unroll
  for (int i = 0; i < 4; i++) {
#pragma unroll
    for (int r = 0; r < 4; r++) rowp[i][r] = 0.0f;
#pragma unroll
    for (int j = 0; j < 4; j++) {
      const int col = n0 + wn + j * 16 + ln;
#pragma unroll
      for (int r = 0; r < 4; r++) {
        const int row = m0 + wm + i * 16 + quad * 4 + r;
        float p = 0.0f;
        if (col <= row) p = __expf(acc[i][j][r] * scale);
        const ushort pk = f2bf(p);
        smem[(wm + i * 16 + quad * 4 + r) * 136 + wn + j * 16 + ln] = pk;
        rowp[i][r] += bf2f(pk);
      }
    }
  }
#pragma unroll
  for (int i = 0; i < 4; i++)
#pragma unroll
    for (int r = 0; r < 4; r++) {
      float s = rowp[i][r];
      s += __shfl_xor(s, 1);
      s += __shfl_xor(s, 2);
      s += __shfl_xor(s, 4);
      s += __shfl_xor(s, 8);
      if (ln == 0)
        atomicAdd(ls + b * SEQ + m0 + wm + i * 16 + quad * 4 + r, s);
    }
  __syncthreads();
  ushort* pt = pb + ((size_t)(b * 528 + pr) << 14);
#pragma unroll
  for (int p = 0; p < 8; p++) {
    const int tt = p * 256 + tid;
    const int row = tt >> 4, col = (tt & 15) * 8;
    ushort8 v = *(const ushort8*)&smem[row * 136 + col];
    *(ushort8*)(pt + row * 128 + col) = v;
  }
}

// ---------- kernel 3: O = P_hat @ V, divide by l (BK=64, serpentine) ----------
__global__ __launch_bounds__(256, 4)
void attn_pv(const ushort* __restrict__ pb, const ushort* __restrict__ vt,
             const float* __restrict__ ls, float* __restrict__ out) {
  __shared__ ushort smem[16384];
  ushort* As = smem;
  ushort* Bs = smem + 8192;

  // serpentine rank -> (mt desc, et, b): balances per-CU work at 3 blocks/CU
  int idx = blockIdx.x;
  int chunk = idx >> 8, pos = idx & 255;
  if (chunk & 1) pos = 255 - pos;
  const int r_ = (chunk << 8) + pos;
  const int mt = 31 - r_ / 24;
  const int rem = r_ % 24;
  const int b = rem & 3;
  const int et = rem >> 2;
  const int m0 = mt * 128, e0 = et * 128;

  const int tid = threadIdx.x;
  const int w = tid >> 6, lane = tid & 63, ln = lane & 15, quad = lane >> 4;
  const int wm = (w >> 1) * 64, wn = (w & 1) * 64;
  const size_t vtbase = (size_t)b * DIM * SEQ;
  const ushort* ptiles = pb + ((size_t)(b * 528 + mt * (mt + 1) / 2) << 14);

  const int c0 = w * 128 + lane;
  const int c1 = c0 + 64;
  const int R0 = c0 >> 2, kl0 = (c0 & 3) ^ ((R0 >> 1) & 3);
  const int R1 = c1 >> 2, kl1 = (c1 & 3) ^ ((R1 >> 1) & 3);
  const ushort* ag0 = ptiles + R0 * 128 + kl0 * 8;
  const ushort* ag1 = ptiles + R1 * 128 + kl1 * 8;
  const ushort* bg0 = vt + vtbase + (size_t)(e0 + R0) * SEQ + kl0 * 8;
  const ushort* bg1 = vt + vtbase + (size_t)(e0 + R1) * SEQ + kl1 * 8;
  ushort* al0 = As + (size_t)(w * 128) * 8;
  ushort* al1 = As + (size_t)(w * 128 + 64) * 8;
  ushort* bl0 = Bs + (size_t)(w * 128) * 8;
  ushort* bl1 = Bs + (size_t)(w * 128 + 64) * 8;

  const int sw = quad ^ ((ln >> 1) & 3);
  int aoff[4], boff[4];
#pragma unroll
  for (int i = 0; i < 4; i++) aoff[i] = ((wm + i * 16 + ln) * 4 + sw) * 8;
#pragma unroll
  for (int i = 0; i < 4; i++) boff[i] = ((wn + i * 16 + ln) * 4 + sw) * 8;

  fx4 acc[4][4];
#pragma unroll
  for (int i = 0; i < 4; i++)
#pragma unroll
    for (int j = 0; j < 4; j++) acc[i][j] = (fx4)0.0f;

  const int nk = (mt + 1) * 2;  // 64-wide k-steps
  for (int ks = 0; ks < nk; ks++) {
    const int ntile = ks >> 1;
    const int kin = (ks & 1) * 64;
    const size_t atile = (size_t)ntile * 16384 + kin;
    const int kglob = ntile * 128 + kin;
    gload_lds16(ag0 + atile, al0);
    gload_lds16(ag1 + atile, al1);
    gload_lds16(ag0 + atile + 32, al0 + 4096);
    gload_lds16(ag1 + atile + 32, al1 + 4096);
    gload_lds16(bg0 + kglob, bl0);
    gload_lds16(bg1 + kglob, bl1);
    gload_lds16(bg0 + kglob + 32, bl0 + 4096);
    gload_lds16(bg1 + kglob + 32, bl1 + 4096);
    __syncthreads();
#pragma unroll
    for (int h = 0; h < 2; h++) {
      const int hb = h * 4096;
      short8 af[4], bf[4];
#pragma unroll
      for (int i = 0; i < 4; i++) af[i] = *(const short8*)(As + hb + aoff[i]);
#pragma unroll
      for (int i = 0; i < 4; i++) bf[i] = *(const short8*)(Bs + hb + boff[i]);
#pragma unroll
      for (int i = 0; i < 4; i++)
#pragma unroll
        for (int j = 0; j < 4; j++)
          acc[i][j] = MFMA16(af[i], bf[j], acc[i][j]);
    }
    __syncthreads();
  }

#pragma unroll
  for (int i = 0; i < 4; i++)
#pragma unroll
    for (int r = 0; r < 4; r++) {
      const int row = m0 + wm + i * 16 + quad * 4 + r;
      const float linv = 1.0f / ls[b * SEQ + row];
      float* orow = out + ((size_t)(b * SEQ + row)) * DIM + e0 + wn + ln;
#pragma unroll
      for (int j = 0; j < 4; j++) orow[j * 16] = acc[i][j][r] * linv;
    }
}

extern "C" void kernel_launch(void* const* d_in, const int* in_sizes, int n_in,
                              void* d_out, int out_size, void* d_ws, size_t ws_size,
                              hipStream_t stream) {
  const float* x = (const float*)d_in[0];
  const float* wq = (const float*)d_in[1];
  const float* wk = (const float*)d_in[2];
  const float* wv = (const float*)d_in[3];
  float* out = (float*)d_out;

  ushort* qb = (ushort*)d_ws;
  ushort* kb = qb + 12582912;
  ushort* vt = kb + 12582912;
  ushort* xb = vt + 12582912;
  ushort* wb = xb + 12582912;
  ushort* pb = xb;  // alias: xb/wb dead after qkv_proj
  float* ls = (float*)((ushort*)d_ws + 72351744);

  cvt_all<<<7008, 256, 0, stream>>>(x, wq, wk, wv, xb, wb, ls);
  qkv_proj<<<dim3(128, 18), 256, 0, stream>>>(xb, wb, qb, kb, vt);
  attn_scores<<<dim3(528, 4), 256, 0, stream>>>(qb, kb, pb, ls);
  attn_pv<<<768, 256, 0, stream>>>(pb, vt, ls, out);
}